// Round 14
// baseline (574.429 us; speedup 1.0000x reference)
//
#include <hip/hip_runtime.h>
#include <float.h>

// VectorQuantize: h=8 heads, c=2048 codes, d=64, b=8, t=2048 (n=16384 vec/head)
#define H   8
#define C   2048
#define D   64
#define NPH 16384     // vectors per head (b*t)
#define HD  512       // h*d
#define DECAYF 0.9f
#define DELTA 3.0f    // candidate margin >= 2x worst-case bf16 score error (~0.6)
#define CAP 96        // per-vector candidate slots
#define VB  256       // vectors per block (512 blocks; R13's VB=128 halved
                      // per-B-load intensity and regressed -- reverted)

typedef __attribute__((ext_vector_type(8))) short short8v;   // 8 bf16 (4 VGPR)
typedef __attribute__((ext_vector_type(4))) float f32x4;

__device__ inline unsigned short f32_to_bf16_rne(float f) {
    unsigned int x = __float_as_uint(f);
    return (unsigned short)((x + 0x7FFFu + ((x >> 16) & 1u)) >> 16);
}

// ---------------------------------------------------------------------------
// Kernel 0: fused prep. Thread = one codebook row: keb[row][*] = bf16(ke),
// esq[row] = serial-fmaf sum of squares (bit-identical chain to all passing
// rounds -- esq feeds the EXACT rescore, so its rounding must not change).
// ---------------------------------------------------------------------------
__global__ __launch_bounds__(256) void vq_prep_kernel(const float* __restrict__ ke,
                                                      unsigned short* __restrict__ keb,
                                                      float* __restrict__ esq) {
    const int row = blockIdx.x * 256 + threadIdx.x;   // 0 .. H*C-1
    const float* e = ke + (size_t)row * D;
    unsigned short* kb = keb + (size_t)row * D;
    float s = 0.f;
#pragma unroll
    for (int i = 0; i < 8; ++i) {
        float4 v0 = ((const float4*)e)[2 * i];
        float4 v1 = ((const float4*)e)[2 * i + 1];
        short8v o;
        o[0] = (short)f32_to_bf16_rne(v0.x); o[1] = (short)f32_to_bf16_rne(v0.y);
        o[2] = (short)f32_to_bf16_rne(v0.z); o[3] = (short)f32_to_bf16_rne(v0.w);
        o[4] = (short)f32_to_bf16_rne(v1.x); o[5] = (short)f32_to_bf16_rne(v1.y);
        o[6] = (short)f32_to_bf16_rne(v1.z); o[7] = (short)f32_to_bf16_rne(v1.w);
        *(short8v*)(kb + 8 * i) = o;
    }
#pragma unroll
    for (int d = 0; d < D; ++d) s = fmaf(e[d], e[d], s);
    esq[row] = s;
}

// ---------------------------------------------------------------------------
// Kernel 1: SINGLE-PASS MFMA screening + exact rescore.
//   R14: one scan instead of two (running-min threshold: superset guarantee
//   since running min >= final min; set deterministic; rescore min is
//   order-independent). 8 warm-up chunks (min-only) + cross-lane sync keep
//   candidate counts small; scan then covers chunks 8..135 mod 128 (each
//   chunk exactly once, collecting). Overflow (>CAP) -> block-local repair
//   pass with tight final min; per-thread full exact scan only as ultimate
//   fallback. 2-slot named-register pipeline (R13's array slots were
//   coalesced away by the allocator, VGPR=56 -> serialized loads).
//   512 blocks x 256 thr: blk&7 = head, 256 vec/block, wave w: vecs w*64..+63.
//   Exact rescore per vec: serial fmaf k-ascending, fmaf(-2,dot,esq),
//   lexicographic (score,idx) min -- bit-identical to passing R7-R13.
// ---------------------------------------------------------------------------
__global__ __launch_bounds__(256, 2)
void vq_main_kernel(const float* __restrict__ x,
                    const unsigned short* __restrict__ keb,
                    const float* __restrict__ ke,
                    const float* __restrict__ esq,
                    float* __restrict__ outq,
                    float* __restrict__ outi,
                    unsigned short* __restrict__ indw,
                    unsigned int* __restrict__ counts) {
    __shared__ int            ccnt[VB];
    __shared__ unsigned short cand[VB][CAP];
    __shared__ int            sflag[VB];
    __shared__ int            sidx[VB];
    __shared__ int            oflow;

    const int tid  = threadIdx.x;
    const int lane = tid & 63;
    const int w    = __builtin_amdgcn_readfirstlane(tid >> 6);
    const int h    = blockIdx.x & 7;
    const int n0   = (blockIdx.x >> 3) * VB;

    const unsigned short* kebh = keb + (size_t)h * C * D;
    const float* keh  = ke  + (size_t)h * C * D;
    const float* esqh = esq + (size_t)h * C;

    ccnt[tid] = 0;
    if (tid == 0) oflow = 0;
    __syncthreads();

    const int col = lane & 15;        // code col within 16-tile
    const int kg  = (lane >> 4) * 8;  // this lane's k-group base

    // ---- A-frags: lane's 4 vec-rows x 64 k, bf16, persistent ----
    short8v afr[4][2];
#pragma unroll
    for (int vt = 0; vt < 4; ++vt) {
        const float* xp = x + (size_t)(n0 + w * 64 + vt * 16 + col) * HD
                            + (size_t)h * D + kg;
#pragma unroll
        for (int kf = 0; kf < 2; ++kf) {
            float4 u0 = *(const float4*)(xp + kf * 32);
            float4 u1 = *(const float4*)(xp + kf * 32 + 4);
            short8v a;
            a[0] = (short)f32_to_bf16_rne(u0.x); a[1] = (short)f32_to_bf16_rne(u0.y);
            a[2] = (short)f32_to_bf16_rne(u0.z); a[3] = (short)f32_to_bf16_rne(u0.w);
            a[4] = (short)f32_to_bf16_rne(u1.x); a[5] = (short)f32_to_bf16_rne(u1.y);
            a[6] = (short)f32_to_bf16_rne(u1.z); a[7] = (short)f32_to_bf16_rne(u1.w);
            afr[vt][kf] = a;
        }
    }

    float amin[16];
#pragma unroll
    for (int s = 0; s < 16; ++s) amin[s] = FLT_MAX;

#define LOADB16(CB, B0, B1, EQ)                                                \
    {                                                                          \
        const unsigned short* kb = kebh + (size_t)((CB) + col) * D + kg;       \
        B0 = *(const short8v*)(kb);                                            \
        B1 = *(const short8v*)(kb + 32);                                       \
        EQ = esqh[(CB) + col];                                                 \
    }

    // EPI: MFMA the chunk, update running min; optionally collect candidates.
#define EPI(C0V, C1V, QV, CB, DOCOLLECT)                                       \
    {                                                                          \
        _Pragma("unroll")                                                      \
        for (int vt = 0; vt < 4; ++vt) {                                       \
            f32x4 acc = {0.f, 0.f, 0.f, 0.f};                                  \
            acc = __builtin_amdgcn_mfma_f32_16x16x32_bf16(afr[vt][0], C0V, acc, 0, 0, 0); \
            acc = __builtin_amdgcn_mfma_f32_16x16x32_bf16(afr[vt][1], C1V, acc, 0, 0, 0); \
            _Pragma("unroll")                                                  \
            for (int r = 0; r < 4; ++r) {                                      \
                const int s = vt * 4 + r;                                      \
                float sc = fmaf(-2.f, acc[r], QV);                             \
                if (sc < amin[s]) amin[s] = sc;                                \
                if (DOCOLLECT && sc <= amin[s] + DELTA) {                      \
                    const int vec = w * 64 + vt * 16 + ((lane >> 4) << 2) + r; \
                    int pos = atomicAdd(&ccnt[vec], 1);                        \
                    if (pos < CAP) cand[vec][pos] = (unsigned short)((CB) + col); \
                }                                                              \
            }                                                                  \
        }                                                                      \
    }

#define SYNC_AMIN                                                              \
    {                                                                          \
        _Pragma("unroll")                                                      \
        for (int s = 0; s < 16; ++s) {                                         \
            float v = amin[s];                                                 \
            v = fminf(v, __shfl_xor(v, 1));                                    \
            v = fminf(v, __shfl_xor(v, 2));                                    \
            v = fminf(v, __shfl_xor(v, 4));                                    \
            v = fminf(v, __shfl_xor(v, 8));                                    \
            amin[s] = v;                                                       \
        }                                                                      \
    }

    // 2-slot pipeline state (named registers -> allocator can't coalesce away)
    short8v Ac0, Ac1, Bc0, Bc1;
    float   Aq, Bq;
    LOADB16(0 << 4, Ac0, Ac1, Aq);
    LOADB16(1 << 4, Bc0, Bc1, Bq);

    // ---- warm-up: chunks 0..7, min-only ----
#pragma unroll 1
    for (int g = 0; g < 4; ++g) {
        {
            short8v c0 = Ac0, c1 = Ac1; float q = Aq;
            LOADB16(((2 * g + 2) & 127) << 4, Ac0, Ac1, Aq);
            EPI(c0, c1, q, 0, false);
        }
        {
            short8v c0 = Bc0, c1 = Bc1; float q = Bq;
            LOADB16(((2 * g + 3) & 127) << 4, Bc0, Bc1, Bq);
            EPI(c0, c1, q, 0, false);
        }
    }
    SYNC_AMIN;   // global-128-code min per vec: tight-ish collection threshold

    // ---- main scan: chunks 8..135 mod 128 (each chunk once, collecting) ----
#pragma unroll 1
    for (int g = 0; g < 64; ++g) {
        {
            const int cb = ((8 + 2 * g) & 127) << 4;
            short8v c0 = Ac0, c1 = Ac1; float q = Aq;
            LOADB16(((2 * g + 10) & 127) << 4, Ac0, Ac1, Aq);
            EPI(c0, c1, q, cb, true);
        }
        {
            const int cb = ((9 + 2 * g) & 127) << 4;
            short8v c0 = Bc0, c1 = Bc1; float q = Bq;
            LOADB16(((2 * g + 11) & 127) << 4, Bc0, Bc1, Bq);
            EPI(c0, c1, q, cb, true);
        }
    }
    SYNC_AMIN;   // final global approx min per vec (for repair threshold)
    __syncthreads();

    // ---- overflow detection ----
    if (ccnt[tid] > CAP) { sflag[tid] = 1; ccnt[tid] = 0; oflow = 1; }
    else sflag[tid] = 0;
    __syncthreads();

    // ---- rare block-local repair: re-collect flagged vecs w/ tight min ----
    if (oflow) {
#pragma unroll 1
        for (int ch = 0; ch < 128; ++ch) {
            short8v c0, c1; float q;
            LOADB16(ch << 4, c0, c1, q);
#pragma unroll
            for (int vt = 0; vt < 4; ++vt) {
                f32x4 acc = {0.f, 0.f, 0.f, 0.f};
                acc = __builtin_amdgcn_mfma_f32_16x16x32_bf16(afr[vt][0], c0, acc, 0, 0, 0);
                acc = __builtin_amdgcn_mfma_f32_16x16x32_bf16(afr[vt][1], c1, acc, 0, 0, 0);
#pragma unroll
                for (int r = 0; r < 4; ++r) {
                    const int s = vt * 4 + r;
                    const int vec = w * 64 + vt * 16 + ((lane >> 4) << 2) + r;
                    float sc = fmaf(-2.f, acc[r], q);
                    if (sflag[vec] && sc <= amin[s] + DELTA) {
                        int pos = atomicAdd(&ccnt[vec], 1);
                        if (pos < CAP) cand[vec][pos] = (unsigned short)((ch << 4) + col);
                    }
                }
            }
        }
        __syncthreads();
    }

    // ---- exact f32 rescore: thread tid <-> vec tid ----
    {
        const float4* xr = (const float4*)(x + (size_t)(n0 + tid) * HD + (size_t)h * D);
        const int nc = ccnt[tid];
        float bb = FLT_MAX;
        int   bi = 0x7fffffff;
        if (nc <= CAP) {
            for (int i = 0; i < nc; ++i) {
                const int code = cand[tid][i];
                const float4* er = (const float4*)(keh + (size_t)code * D);
                float s = 0.f;
#pragma unroll 4
                for (int kq = 0; kq < 16; ++kq) {
                    float4 a4 = xr[kq]; float4 e4 = er[kq];
                    s = fmaf(a4.x, e4.x, s); s = fmaf(a4.y, e4.y, s);
                    s = fmaf(a4.z, e4.z, s); s = fmaf(a4.w, e4.w, s);
                }
                float sc = fmaf(-2.f, s, esqh[code]);
                if (sc < bb || (sc == bb && code < bi)) { bb = sc; bi = code; }
            }
        } else {
            // ultimate fallback: full exact scan, ascending => first-min
            for (int code = 0; code < C; ++code) {
                const float4* er = (const float4*)(keh + (size_t)code * D);
                float s = 0.f;
#pragma unroll 4
                for (int kq = 0; kq < 16; ++kq) {
                    float4 a4 = xr[kq]; float4 e4 = er[kq];
                    s = fmaf(a4.x, e4.x, s); s = fmaf(a4.y, e4.y, s);
                    s = fmaf(a4.z, e4.z, s); s = fmaf(a4.w, e4.w, s);
                }
                float sc = fmaf(-2.f, s, esqh[code]);
                if (sc < bb) { bb = sc; bi = code; }
            }
        }
        sidx[tid] = bi;
        outi[(size_t)(n0 + tid) * H + h] = (float)bi;          // [b,t,h]
        indw[((size_t)h << 14) + n0 + tid] = (unsigned short)bi;
        atomicAdd(&counts[(h << 11) + bi], 1u);                // fused histogram
    }
    __syncthreads();

    // ---- gather quantized vectors (no atomics) ----
#pragma unroll
    for (int ii = 0; ii < 2; ++ii) {
        const int v  = ii * 128 + (tid >> 1);
        const int db = (tid & 1) * 32;
        const int ci = sidx[v];
        const float* ev = keh + (size_t)ci * D + db;
        float* qo = outq + (size_t)(n0 + v) * HD + (size_t)h * D + db;
#pragma unroll
        for (int i = 0; i < 8; ++i)
            ((float4*)qo)[i] = ((const float4*)ev)[i];
    }
}

// ---------------------------------------------------------------------------
// Kernel 3: per-head exclusive prefix scan of counts -> off, cur
// ---------------------------------------------------------------------------
__global__ __launch_bounds__(256) void vq_scan_kernel(const unsigned int* __restrict__ counts,
                                                      unsigned int* __restrict__ off,
                                                      unsigned int* __restrict__ cur) {
    __shared__ unsigned int sa[C], sb[C];
    const int h   = blockIdx.x;
    const int tid = threadIdx.x;
#pragma unroll
    for (int j = 0; j < 8; ++j) sa[j * 256 + tid] = counts[(h << 11) + j * 256 + tid];
    __syncthreads();
    unsigned int* src = sa;
    unsigned int* dst = sb;
    for (int s = 1; s < C; s <<= 1) {
#pragma unroll
        for (int j = 0; j < 8; ++j) {
            const int c = j * 256 + tid;
            unsigned int v = src[c];
            if (c >= s) v += src[c - s];
            dst[c] = v;
        }
        __syncthreads();
        unsigned int* t = src; src = dst; dst = t;
    }
#pragma unroll
    for (int j = 0; j < 8; ++j) {
        const int c = j * 256 + tid;
        const unsigned int e = c ? src[c - 1] : 0u;
        off[(h << 11) + c] = e;
        cur[(h << 11) + c] = e;
    }
}

// ---------------------------------------------------------------------------
// Kernel 4: scatter vec-ids into per-code lists (131K cursor atomics)
// ---------------------------------------------------------------------------
__global__ __launch_bounds__(256) void vq_scatter_kernel(const unsigned short* __restrict__ ind,
                                                         unsigned int* __restrict__ cur,
                                                         unsigned short* __restrict__ perm) {
    const int g = blockIdx.x * 256 + threadIdx.x;   // 131072
    const int h = g >> 14;
    const int n = g & 16383;
    const int c = ind[g];
    const unsigned int pos = atomicAdd(&cur[(h << 11) + c], 1u);
    perm[((size_t)h << 14) + pos] = (unsigned short)n;
}

// ---------------------------------------------------------------------------
// Kernel 5: segmented reduce + fused EMA lerp. One wave per (head,code);
//   lane = d. f64 accumulation => order-independent after f32 rounding.
// ---------------------------------------------------------------------------
__global__ __launch_bounds__(256) void vq_reduce_kernel(const float* __restrict__ x,
                                                        const float* __restrict__ ke,
                                                        const unsigned short* __restrict__ perm,
                                                        const unsigned int* __restrict__ counts,
                                                        const unsigned int* __restrict__ off,
                                                        const int* __restrict__ ko,
                                                        float* __restrict__ outk) {
    const int tid  = threadIdx.x;
    const int lane = tid & 63;
    const int pair = blockIdx.x * 4 + (tid >> 6);   // == h*2048 + c
    const int h    = pair >> 11;

    const unsigned int cnt = counts[pair];
    const unsigned int o   = off[pair];
    const unsigned short* pl = perm + ((size_t)h << 14) + o;

    double acc = 0.0;
    for (unsigned int i = 0; i < cnt; ++i) {
        const int vid = pl[i];   // wave-uniform broadcast load
        acc += (double)x[(size_t)vid * HD + (size_t)h * D + lane];
    }
    const float esum = (float)acc;
    const float kv   = ke[(size_t)pair * D + lane];
    const float ov   = ko[0] ? (kv + DECAYF * (esum - kv)) : kv;
    outk[(size_t)pair * D + lane] = ov;
}

extern "C" void kernel_launch(void* const* d_in, const int* in_sizes, int n_in,
                              void* d_out, int out_size, void* d_ws, size_t ws_size,
                              hipStream_t stream) {
    const float* x  = (const float*)d_in[0];
    const float* ke = (const float*)d_in[1];
    const int*   ko = (const int*)d_in[2];

    float* out  = (float*)d_out;
    float* outq = out;                                   // 8,388,608 floats
    float* outi = out + (size_t)H * NPH * D;             // +131,072 floats
    float* outk = outi + (size_t)NPH * H;                // +1,048,576 floats

    // workspace layout
    float*          esq    = (float*)d_ws;                              // 16,384 f32
    unsigned short* keb    = (unsigned short*)(esq + H * C);            // 1M u16
    unsigned short* indw   = keb + (size_t)H * C * D;                   // 131,072 u16
    unsigned int*   counts = (unsigned int*)(indw + (size_t)H * NPH);   // 16,384 u32
    unsigned int*   offv   = counts + H * C;                            // 16,384 u32
    unsigned int*   curv   = offv + H * C;                              // 16,384 u32
    unsigned short* perm   = (unsigned short*)(curv + H * C);           // 131,072 u16

    hipMemsetAsync(counts, 0, (size_t)H * C * sizeof(unsigned int), stream);

    vq_prep_kernel<<<(H * C) / 256, 256, 0, stream>>>(ke, keb, esq);
    vq_main_kernel<<<512, 256, 0, stream>>>(x, keb, ke, esq, outq, outi, indw, counts);
    vq_scan_kernel<<<H, 256, 0, stream>>>(counts, offv, curv);
    vq_scatter_kernel<<<512, 256, 0, stream>>>(indw, curv, perm);
    vq_reduce_kernel<<<(H * C) / 4, 256, 0, stream>>>(x, ke, perm, counts, offv, ko, outk);
}

// Round 15
// 352.957 us; speedup vs baseline: 1.6275x; 1.6275x over previous
//
#include <hip/hip_runtime.h>
#include <float.h>

// VectorQuantize: h=8 heads, c=2048 codes, d=64, b=8, t=2048 (n=16384 vec/head)
#define H   8
#define C   2048
#define D   64
#define NPH 16384     // vectors per head (b*t)
#define HD  512       // h*d
#define DECAYF 0.9f
#define DELTA 3.0f    // candidate margin >= 2x worst-case bf16 score error (~0.6)
#define CAP 64        // per-vector candidate slots (R12 value; R14's 96 blew LDS)
#define VB  256       // vectors per block (512 blocks)

typedef __attribute__((ext_vector_type(8))) short short8v;   // 8 bf16 (4 VGPR)
typedef __attribute__((ext_vector_type(4))) float f32x4;

__device__ inline unsigned short f32_to_bf16_rne(float f) {
    unsigned int x = __float_as_uint(f);
    return (unsigned short)((x + 0x7FFFu + ((x >> 16) & 1u)) >> 16);
}

// ---------------------------------------------------------------------------
// Kernel 0: fused prep. Thread = one codebook row r = (h, ch*16+c):
//   esq[r]  = serial-fmaf sum of squares (bit-identical to passing rounds)
//   keb2    = bf16 codebook PRE-SWIZZLED into MFMA-fragment-linear order:
//     keb2h[ch*1024 + kf*512 + (g*16 + c)*8 + j] = bf16(ke[ch*16+c][kf*32+g*8+j])
//   so main's B-load is keb2h[ch*1024 + lane*8] (+512): two fully-coalesced
//   1KB wave-loads per chunk. R12's code-major loads were 16B/lane at 128B
//   stride (scattered L2 transactions) -- the 5x-above-issue-limit stall.
// ---------------------------------------------------------------------------
__global__ __launch_bounds__(256) void vq_prep_kernel(const float* __restrict__ ke,
                                                      unsigned short* __restrict__ keb2,
                                                      float* __restrict__ esq) {
    const int row = blockIdx.x * 256 + threadIdx.x;   // 0 .. H*C-1
    const int c   = row & 15;
    const int ch  = (row >> 4) & 127;
    const int h   = row >> 11;
    const float* e = ke + (size_t)row * D;
    unsigned short* kb = keb2 + ((size_t)h * C * D) + (size_t)ch * 1024;
#pragma unroll
    for (int kf = 0; kf < 2; ++kf)
#pragma unroll
        for (int g = 0; g < 4; ++g) {
            float4 v0 = ((const float4*)e)[kf * 8 + g * 2];
            float4 v1 = ((const float4*)e)[kf * 8 + g * 2 + 1];
            short8v o;
            o[0] = (short)f32_to_bf16_rne(v0.x); o[1] = (short)f32_to_bf16_rne(v0.y);
            o[2] = (short)f32_to_bf16_rne(v0.z); o[3] = (short)f32_to_bf16_rne(v0.w);
            o[4] = (short)f32_to_bf16_rne(v1.x); o[5] = (short)f32_to_bf16_rne(v1.y);
            o[6] = (short)f32_to_bf16_rne(v1.z); o[7] = (short)f32_to_bf16_rne(v1.w);
            *(short8v*)(kb + kf * 512 + (g * 16 + c) * 8) = o;
        }
    float s = 0.f;
#pragma unroll
    for (int d = 0; d < D; ++d) s = fmaf(e[d], e[d], s);
    esq[row] = s;
}

// ---------------------------------------------------------------------------
// Kernel 1: MFMA screening + exact rescore (R12 two-pass structure verbatim;
//   only the B addressing changed to the swizzled-linear layout + named
//   2-deep A/B prefetch). 512 blocks x 256 thr: blk&7 = head, 256 vec/block,
//   wave w: vecs w*64..+63. Candidates per-VECTOR (R10 lesson), CAP=64,
//   fused histogram, exact f32 rescore (serial fmaf k-ascending,
//   fmaf(-2,dot,esq), lexicographic (score,idx) min) -- all as passing R12.
// ---------------------------------------------------------------------------
__global__ __launch_bounds__(256, 2)
void vq_main_kernel(const float* __restrict__ x,
                    const unsigned short* __restrict__ keb2,
                    const float* __restrict__ ke,
                    const float* __restrict__ esq,
                    float* __restrict__ outq,
                    float* __restrict__ outi,
                    unsigned short* __restrict__ indw,
                    unsigned int* __restrict__ counts) {
    __shared__ int            ccnt[VB];
    __shared__ unsigned short cand[VB][CAP];
    __shared__ int            sidx[VB];

    const int tid  = threadIdx.x;
    const int lane = tid & 63;
    const int w    = __builtin_amdgcn_readfirstlane(tid >> 6);
    const int h    = blockIdx.x & 7;
    const int n0   = (blockIdx.x >> 3) * VB;

    const unsigned short* keb2h = keb2 + (size_t)h * C * D;
    const float* keh  = ke  + (size_t)h * C * D;
    const float* esqh = esq + (size_t)h * C;

    ccnt[tid] = 0;
    __syncthreads();

    const int col = lane & 15;        // code col within 16-tile
    const int kg  = (lane >> 4) * 8;  // this lane's k-group base

    // ---- A-frags: lane's 4 vec-rows x 64 k, bf16, persistent ----
    short8v afr[4][2];
#pragma unroll
    for (int vt = 0; vt < 4; ++vt) {
        const float* xp = x + (size_t)(n0 + w * 64 + vt * 16 + col) * HD
                            + (size_t)h * D + kg;
#pragma unroll
        for (int kf = 0; kf < 2; ++kf) {
            float4 u0 = *(const float4*)(xp + kf * 32);
            float4 u1 = *(const float4*)(xp + kf * 32 + 4);
            short8v a;
            a[0] = (short)f32_to_bf16_rne(u0.x); a[1] = (short)f32_to_bf16_rne(u0.y);
            a[2] = (short)f32_to_bf16_rne(u0.z); a[3] = (short)f32_to_bf16_rne(u0.w);
            a[4] = (short)f32_to_bf16_rne(u1.x); a[5] = (short)f32_to_bf16_rne(u1.y);
            a[6] = (short)f32_to_bf16_rne(u1.z); a[7] = (short)f32_to_bf16_rne(u1.w);
            afr[vt][kf] = a;
        }
    }

    float amin[16];
#pragma unroll
    for (int s = 0; s < 16; ++s) amin[s] = FLT_MAX;

    // coalesced fragment load: B0 = kb[lane], B1 = kb[64+lane]
#define LOADB2(CH, B0, B1, EQ)                                                 \
    {                                                                          \
        const short8v* kb = (const short8v*)(keb2h + (size_t)(CH) * 1024);     \
        B0 = kb[lane];                                                         \
        B1 = kb[64 + lane];                                                    \
        EQ = esqh[((CH) << 4) + col];                                          \
    }

    // ================= pass 1: per-vector approx min =================
    {
        short8v Ac0, Ac1, Bc0, Bc1; float Aq, Bq;
        LOADB2(0, Ac0, Ac1, Aq);
        LOADB2(1, Bc0, Bc1, Bq);
#pragma unroll 1
        for (int g = 0; g < 64; ++g) {
            {
                short8v c0 = Ac0, c1 = Ac1; float q = Aq;
                LOADB2((2 * g + 2) & 127, Ac0, Ac1, Aq);
#pragma unroll
                for (int vt = 0; vt < 4; ++vt) {
                    f32x4 acc = {0.f, 0.f, 0.f, 0.f};
                    acc = __builtin_amdgcn_mfma_f32_16x16x32_bf16(afr[vt][0], c0, acc, 0, 0, 0);
                    acc = __builtin_amdgcn_mfma_f32_16x16x32_bf16(afr[vt][1], c1, acc, 0, 0, 0);
#pragma unroll
                    for (int r = 0; r < 4; ++r) {
                        float sc = fmaf(-2.f, acc[r], q);
                        amin[vt * 4 + r] = fminf(amin[vt * 4 + r], sc);
                    }
                }
            }
            {
                short8v c0 = Bc0, c1 = Bc1; float q = Bq;
                LOADB2((2 * g + 3) & 127, Bc0, Bc1, Bq);
#pragma unroll
                for (int vt = 0; vt < 4; ++vt) {
                    f32x4 acc = {0.f, 0.f, 0.f, 0.f};
                    acc = __builtin_amdgcn_mfma_f32_16x16x32_bf16(afr[vt][0], c0, acc, 0, 0, 0);
                    acc = __builtin_amdgcn_mfma_f32_16x16x32_bf16(afr[vt][1], c1, acc, 0, 0, 0);
#pragma unroll
                    for (int r = 0; r < 4; ++r) {
                        float sc = fmaf(-2.f, acc[r], q);
                        amin[vt * 4 + r] = fminf(amin[vt * 4 + r], sc);
                    }
                }
            }
        }
    }

    // cross-lane min over the 16 lanes sharing (lane>>4)
#pragma unroll
    for (int s = 0; s < 16; ++s) {
        float v = amin[s];
        v = fminf(v, __shfl_xor(v, 1));
        v = fminf(v, __shfl_xor(v, 2));
        v = fminf(v, __shfl_xor(v, 4));
        v = fminf(v, __shfl_xor(v, 8));
        amin[s] = v;
    }

    // ================= pass 2: collect candidates per VECTOR ================
    {
        short8v Ac0, Ac1, Bc0, Bc1; float Aq, Bq;
        LOADB2(0, Ac0, Ac1, Aq);
        LOADB2(1, Bc0, Bc1, Bq);
#pragma unroll 1
        for (int g = 0; g < 64; ++g) {
#pragma unroll
            for (int half = 0; half < 2; ++half) {
                const int ch = 2 * g + half;
                short8v c0, c1; float q;
                if (half == 0) {
                    c0 = Ac0; c1 = Ac1; q = Aq;
                    LOADB2((ch + 2) & 127, Ac0, Ac1, Aq);
                } else {
                    c0 = Bc0; c1 = Bc1; q = Bq;
                    LOADB2((ch + 2) & 127, Bc0, Bc1, Bq);
                }
                const int cb = ch << 4;
#pragma unroll
                for (int vt = 0; vt < 4; ++vt) {
                    f32x4 acc = {0.f, 0.f, 0.f, 0.f};
                    acc = __builtin_amdgcn_mfma_f32_16x16x32_bf16(afr[vt][0], c0, acc, 0, 0, 0);
                    acc = __builtin_amdgcn_mfma_f32_16x16x32_bf16(afr[vt][1], c1, acc, 0, 0, 0);
#pragma unroll
                    for (int r = 0; r < 4; ++r) {
                        float sc = fmaf(-2.f, acc[r], q);
                        if (sc <= amin[vt * 4 + r] + DELTA) {
                            const int vec = w * 64 + vt * 16 + ((lane >> 4) << 2) + r;
                            int pos = atomicAdd(&ccnt[vec], 1);
                            if (pos < CAP) cand[vec][pos] = (unsigned short)(cb + col);
                        }
                    }
                }
            }
        }
    }
    __syncthreads();

    // ================= exact f32 rescore: thread tid <-> vec tid ============
    {
        const float4* xr = (const float4*)(x + (size_t)(n0 + tid) * HD + (size_t)h * D);
        const int nc = ccnt[tid];
        float bb = FLT_MAX;
        int   bi = 0x7fffffff;
        if (nc <= CAP) {
            for (int i = 0; i < nc; ++i) {
                const int code = cand[tid][i];
                const float4* er = (const float4*)(keh + (size_t)code * D);
                float s = 0.f;
#pragma unroll 4
                for (int kq = 0; kq < 16; ++kq) {
                    float4 a4 = xr[kq]; float4 e4 = er[kq];
                    s = fmaf(a4.x, e4.x, s); s = fmaf(a4.y, e4.y, s);
                    s = fmaf(a4.z, e4.z, s); s = fmaf(a4.w, e4.w, s);
                }
                float sc = fmaf(-2.f, s, esqh[code]);
                if (sc < bb || (sc == bb && code < bi)) { bb = sc; bi = code; }
            }
        } else {
            // deterministic fallback: full exact scan, ascending => first-min
            for (int code = 0; code < C; ++code) {
                const float4* er = (const float4*)(keh + (size_t)code * D);
                float s = 0.f;
#pragma unroll 4
                for (int kq = 0; kq < 16; ++kq) {
                    float4 a4 = xr[kq]; float4 e4 = er[kq];
                    s = fmaf(a4.x, e4.x, s); s = fmaf(a4.y, e4.y, s);
                    s = fmaf(a4.z, e4.z, s); s = fmaf(a4.w, e4.w, s);
                }
                float sc = fmaf(-2.f, s, esqh[code]);
                if (sc < bb) { bb = sc; bi = code; }
            }
        }
        sidx[tid] = bi;
        outi[(size_t)(n0 + tid) * H + h] = (float)bi;          // [b,t,h]
        indw[((size_t)h << 14) + n0 + tid] = (unsigned short)bi;
        atomicAdd(&counts[(h << 11) + bi], 1u);                // fused histogram
    }
    __syncthreads();

    // ---- gather quantized vectors (no atomics) ----
#pragma unroll
    for (int ii = 0; ii < 2; ++ii) {
        const int v  = ii * 128 + (tid >> 1);
        const int db = (tid & 1) * 32;
        const int ci = sidx[v];
        const float* ev = keh + (size_t)ci * D + db;
        float* qo = outq + (size_t)(n0 + v) * HD + (size_t)h * D + db;
#pragma unroll
        for (int i = 0; i < 8; ++i)
            ((float4*)qo)[i] = ((const float4*)ev)[i];
    }
}

// ---------------------------------------------------------------------------
// Kernel 3: per-head exclusive prefix scan of counts -> off, cur
// ---------------------------------------------------------------------------
__global__ __launch_bounds__(256) void vq_scan_kernel(const unsigned int* __restrict__ counts,
                                                      unsigned int* __restrict__ off,
                                                      unsigned int* __restrict__ cur) {
    __shared__ unsigned int sa[C], sb[C];
    const int h   = blockIdx.x;
    const int tid = threadIdx.x;
#pragma unroll
    for (int j = 0; j < 8; ++j) sa[j * 256 + tid] = counts[(h << 11) + j * 256 + tid];
    __syncthreads();
    unsigned int* src = sa;
    unsigned int* dst = sb;
    for (int s = 1; s < C; s <<= 1) {
#pragma unroll
        for (int j = 0; j < 8; ++j) {
            const int c = j * 256 + tid;
            unsigned int v = src[c];
            if (c >= s) v += src[c - s];
            dst[c] = v;
        }
        __syncthreads();
        unsigned int* t = src; src = dst; dst = t;
    }
#pragma unroll
    for (int j = 0; j < 8; ++j) {
        const int c = j * 256 + tid;
        const unsigned int e = c ? src[c - 1] : 0u;
        off[(h << 11) + c] = e;
        cur[(h << 11) + c] = e;
    }
}

// ---------------------------------------------------------------------------
// Kernel 4: scatter vec-ids into per-code lists (131K cursor atomics)
// ---------------------------------------------------------------------------
__global__ __launch_bounds__(256) void vq_scatter_kernel(const unsigned short* __restrict__ ind,
                                                         unsigned int* __restrict__ cur,
                                                         unsigned short* __restrict__ perm) {
    const int g = blockIdx.x * 256 + threadIdx.x;   // 131072
    const int h = g >> 14;
    const int n = g & 16383;
    const int c = ind[g];
    const unsigned int pos = atomicAdd(&cur[(h << 11) + c], 1u);
    perm[((size_t)h << 14) + pos] = (unsigned short)n;
}

// ---------------------------------------------------------------------------
// Kernel 5: segmented reduce + fused EMA lerp. One wave per (head,code);
//   lane = d. f64 accumulation => order-independent after f32 rounding.
// ---------------------------------------------------------------------------
__global__ __launch_bounds__(256) void vq_reduce_kernel(const float* __restrict__ x,
                                                        const float* __restrict__ ke,
                                                        const unsigned short* __restrict__ perm,
                                                        const unsigned int* __restrict__ counts,
                                                        const unsigned int* __restrict__ off,
                                                        const int* __restrict__ ko,
                                                        float* __restrict__ outk) {
    const int tid  = threadIdx.x;
    const int lane = tid & 63;
    const int pair = blockIdx.x * 4 + (tid >> 6);   // == h*2048 + c
    const int h    = pair >> 11;

    const unsigned int cnt = counts[pair];
    const unsigned int o   = off[pair];
    const unsigned short* pl = perm + ((size_t)h << 14) + o;

    double acc = 0.0;
    for (unsigned int i = 0; i < cnt; ++i) {
        const int vid = pl[i];   // wave-uniform broadcast load
        acc += (double)x[(size_t)vid * HD + (size_t)h * D + lane];
    }
    const float esum = (float)acc;
    const float kv   = ke[(size_t)pair * D + lane];
    const float ov   = ko[0] ? (kv + DECAYF * (esum - kv)) : kv;
    outk[(size_t)pair * D + lane] = ov;
}

extern "C" void kernel_launch(void* const* d_in, const int* in_sizes, int n_in,
                              void* d_out, int out_size, void* d_ws, size_t ws_size,
                              hipStream_t stream) {
    const float* x  = (const float*)d_in[0];
    const float* ke = (const float*)d_in[1];
    const int*   ko = (const int*)d_in[2];

    float* out  = (float*)d_out;
    float* outq = out;                                   // 8,388,608 floats
    float* outi = out + (size_t)H * NPH * D;             // +131,072 floats
    float* outk = outi + (size_t)NPH * H;                // +1,048,576 floats

    // workspace layout
    float*          esq    = (float*)d_ws;                              // 16,384 f32
    unsigned short* keb2   = (unsigned short*)(esq + H * C);            // 1M u16 (swizzled)
    unsigned short* indw   = keb2 + (size_t)H * C * D;                  // 131,072 u16
    unsigned int*   counts = (unsigned int*)(indw + (size_t)H * NPH);   // 16,384 u32
    unsigned int*   offv   = counts + H * C;                            // 16,384 u32
    unsigned int*   curv   = offv + H * C;                              // 16,384 u32
    unsigned short* perm   = (unsigned short*)(curv + H * C);           // 131,072 u16

    hipMemsetAsync(counts, 0, (size_t)H * C * sizeof(unsigned int), stream);

    vq_prep_kernel<<<(H * C) / 256, 256, 0, stream>>>(ke, keb2, esq);
    vq_main_kernel<<<512, 256, 0, stream>>>(x, keb2, ke, esq, outq, outi, indw, counts);
    vq_scan_kernel<<<H, 256, 0, stream>>>(counts, offv, curv);
    vq_scatter_kernel<<<512, 256, 0, stream>>>(indw, curv, perm);
    vq_reduce_kernel<<<(H * C) / 4, 256, 0, stream>>>(x, ke, perm, counts, offv, ko, outk);
}

// Round 16
// 211.154 us; speedup vs baseline: 2.7204x; 1.6716x over previous
//
#include <hip/hip_runtime.h>
#include <float.h>

// VectorQuantize: h=8 heads, c=2048 codes, d=64, b=8, t=2048 (n=16384 vec/head)
#define H   8
#define C   2048
#define D   64
#define NPH 16384     // vectors per head (b*t)
#define HD  512       // h*d
#define DECAYF 0.9f
#define DELTA 3.0f    // candidate margin >= 2x worst-case bf16 score error (~0.6)
#define CAP 64        // per-vector candidate slots
#define VB  256       // vectors per block (512 blocks)

typedef __attribute__((ext_vector_type(8))) short short8v;   // 8 bf16 (4 VGPR)
typedef __attribute__((ext_vector_type(4))) float f32x4;

__device__ inline unsigned short f32_to_bf16_rne(float f) {
    unsigned int x = __float_as_uint(f);
    return (unsigned short)((x + 0x7FFFu + ((x >> 16) & 1u)) >> 16);
}

// ---------------------------------------------------------------------------
// Kernel 0: fused prep. Thread = one codebook row r = (h, ch*16+c):
//   esq[r]  = serial-fmaf sum of squares (bit-identical to passing rounds)
//   keb2    = bf16 codebook PRE-SWIZZLED into MFMA-fragment-linear order
//   (R15 win: main's B-load became two coalesced 1KB wave-loads per chunk).
// ---------------------------------------------------------------------------
__global__ __launch_bounds__(256) void vq_prep_kernel(const float* __restrict__ ke,
                                                      unsigned short* __restrict__ keb2,
                                                      float* __restrict__ esq) {
    const int row = blockIdx.x * 256 + threadIdx.x;   // 0 .. H*C-1
    const int c   = row & 15;
    const int ch  = (row >> 4) & 127;
    const int h   = row >> 11;
    const float* e = ke + (size_t)row * D;
    unsigned short* kb = keb2 + ((size_t)h * C * D) + (size_t)ch * 1024;
#pragma unroll
    for (int kf = 0; kf < 2; ++kf)
#pragma unroll
        for (int g = 0; g < 4; ++g) {
            float4 v0 = ((const float4*)e)[kf * 8 + g * 2];
            float4 v1 = ((const float4*)e)[kf * 8 + g * 2 + 1];
            short8v o;
            o[0] = (short)f32_to_bf16_rne(v0.x); o[1] = (short)f32_to_bf16_rne(v0.y);
            o[2] = (short)f32_to_bf16_rne(v0.z); o[3] = (short)f32_to_bf16_rne(v0.w);
            o[4] = (short)f32_to_bf16_rne(v1.x); o[5] = (short)f32_to_bf16_rne(v1.y);
            o[6] = (short)f32_to_bf16_rne(v1.z); o[7] = (short)f32_to_bf16_rne(v1.w);
            *(short8v*)(kb + kf * 512 + (g * 16 + c) * 8) = o;
        }
    float s = 0.f;
#pragma unroll
    for (int d = 0; d < D; ++d) s = fmaf(e[d], e[d], s);
    esq[row] = s;
}

// ---------------------------------------------------------------------------
// Kernel 1: MFMA screening + exact rescore (R15 verbatim -- passed, 352us).
// ---------------------------------------------------------------------------
__global__ __launch_bounds__(256, 2)
void vq_main_kernel(const float* __restrict__ x,
                    const unsigned short* __restrict__ keb2,
                    const float* __restrict__ ke,
                    const float* __restrict__ esq,
                    float* __restrict__ outq,
                    float* __restrict__ outi,
                    unsigned short* __restrict__ indw,
                    unsigned int* __restrict__ counts) {
    __shared__ int            ccnt[VB];
    __shared__ unsigned short cand[VB][CAP];
    __shared__ int            sidx[VB];

    const int tid  = threadIdx.x;
    const int lane = tid & 63;
    const int w    = __builtin_amdgcn_readfirstlane(tid >> 6);
    const int h    = blockIdx.x & 7;
    const int n0   = (blockIdx.x >> 3) * VB;

    const unsigned short* keb2h = keb2 + (size_t)h * C * D;
    const float* keh  = ke  + (size_t)h * C * D;
    const float* esqh = esq + (size_t)h * C;

    ccnt[tid] = 0;
    __syncthreads();

    const int col = lane & 15;        // code col within 16-tile
    const int kg  = (lane >> 4) * 8;  // this lane's k-group base

    // ---- A-frags: lane's 4 vec-rows x 64 k, bf16, persistent ----
    short8v afr[4][2];
#pragma unroll
    for (int vt = 0; vt < 4; ++vt) {
        const float* xp = x + (size_t)(n0 + w * 64 + vt * 16 + col) * HD
                            + (size_t)h * D + kg;
#pragma unroll
        for (int kf = 0; kf < 2; ++kf) {
            float4 u0 = *(const float4*)(xp + kf * 32);
            float4 u1 = *(const float4*)(xp + kf * 32 + 4);
            short8v a;
            a[0] = (short)f32_to_bf16_rne(u0.x); a[1] = (short)f32_to_bf16_rne(u0.y);
            a[2] = (short)f32_to_bf16_rne(u0.z); a[3] = (short)f32_to_bf16_rne(u0.w);
            a[4] = (short)f32_to_bf16_rne(u1.x); a[5] = (short)f32_to_bf16_rne(u1.y);
            a[6] = (short)f32_to_bf16_rne(u1.z); a[7] = (short)f32_to_bf16_rne(u1.w);
            afr[vt][kf] = a;
        }
    }

    float amin[16];
#pragma unroll
    for (int s = 0; s < 16; ++s) amin[s] = FLT_MAX;

    // coalesced fragment load: B0 = kb[lane], B1 = kb[64+lane]
#define LOADB2(CH, B0, B1, EQ)                                                 \
    {                                                                          \
        const short8v* kb = (const short8v*)(keb2h + (size_t)(CH) * 1024);     \
        B0 = kb[lane];                                                         \
        B1 = kb[64 + lane];                                                    \
        EQ = esqh[((CH) << 4) + col];                                          \
    }

    // ================= pass 1: per-vector approx min =================
    {
        short8v Ac0, Ac1, Bc0, Bc1; float Aq, Bq;
        LOADB2(0, Ac0, Ac1, Aq);
        LOADB2(1, Bc0, Bc1, Bq);
#pragma unroll 1
        for (int g = 0; g < 64; ++g) {
            {
                short8v c0 = Ac0, c1 = Ac1; float q = Aq;
                LOADB2((2 * g + 2) & 127, Ac0, Ac1, Aq);
#pragma unroll
                for (int vt = 0; vt < 4; ++vt) {
                    f32x4 acc = {0.f, 0.f, 0.f, 0.f};
                    acc = __builtin_amdgcn_mfma_f32_16x16x32_bf16(afr[vt][0], c0, acc, 0, 0, 0);
                    acc = __builtin_amdgcn_mfma_f32_16x16x32_bf16(afr[vt][1], c1, acc, 0, 0, 0);
#pragma unroll
                    for (int r = 0; r < 4; ++r) {
                        float sc = fmaf(-2.f, acc[r], q);
                        amin[vt * 4 + r] = fminf(amin[vt * 4 + r], sc);
                    }
                }
            }
            {
                short8v c0 = Bc0, c1 = Bc1; float q = Bq;
                LOADB2((2 * g + 3) & 127, Bc0, Bc1, Bq);
#pragma unroll
                for (int vt = 0; vt < 4; ++vt) {
                    f32x4 acc = {0.f, 0.f, 0.f, 0.f};
                    acc = __builtin_amdgcn_mfma_f32_16x16x32_bf16(afr[vt][0], c0, acc, 0, 0, 0);
                    acc = __builtin_amdgcn_mfma_f32_16x16x32_bf16(afr[vt][1], c1, acc, 0, 0, 0);
#pragma unroll
                    for (int r = 0; r < 4; ++r) {
                        float sc = fmaf(-2.f, acc[r], q);
                        amin[vt * 4 + r] = fminf(amin[vt * 4 + r], sc);
                    }
                }
            }
        }
    }

    // cross-lane min over the 16 lanes sharing (lane>>4)
#pragma unroll
    for (int s = 0; s < 16; ++s) {
        float v = amin[s];
        v = fminf(v, __shfl_xor(v, 1));
        v = fminf(v, __shfl_xor(v, 2));
        v = fminf(v, __shfl_xor(v, 4));
        v = fminf(v, __shfl_xor(v, 8));
        amin[s] = v;
    }

    // ================= pass 2: collect candidates per VECTOR ================
    {
        short8v Ac0, Ac1, Bc0, Bc1; float Aq, Bq;
        LOADB2(0, Ac0, Ac1, Aq);
        LOADB2(1, Bc0, Bc1, Bq);
#pragma unroll 1
        for (int g = 0; g < 64; ++g) {
#pragma unroll
            for (int half = 0; half < 2; ++half) {
                const int ch = 2 * g + half;
                short8v c0, c1; float q;
                if (half == 0) {
                    c0 = Ac0; c1 = Ac1; q = Aq;
                    LOADB2((ch + 2) & 127, Ac0, Ac1, Aq);
                } else {
                    c0 = Bc0; c1 = Bc1; q = Bq;
                    LOADB2((ch + 2) & 127, Bc0, Bc1, Bq);
                }
                const int cb = ch << 4;
#pragma unroll
                for (int vt = 0; vt < 4; ++vt) {
                    f32x4 acc = {0.f, 0.f, 0.f, 0.f};
                    acc = __builtin_amdgcn_mfma_f32_16x16x32_bf16(afr[vt][0], c0, acc, 0, 0, 0);
                    acc = __builtin_amdgcn_mfma_f32_16x16x32_bf16(afr[vt][1], c1, acc, 0, 0, 0);
#pragma unroll
                    for (int r = 0; r < 4; ++r) {
                        float sc = fmaf(-2.f, acc[r], q);
                        if (sc <= amin[vt * 4 + r] + DELTA) {
                            const int vec = w * 64 + vt * 16 + ((lane >> 4) << 2) + r;
                            int pos = atomicAdd(&ccnt[vec], 1);
                            if (pos < CAP) cand[vec][pos] = (unsigned short)(cb + col);
                        }
                    }
                }
            }
        }
    }
    __syncthreads();

    // ================= exact f32 rescore: thread tid <-> vec tid ============
    {
        const float4* xr = (const float4*)(x + (size_t)(n0 + tid) * HD + (size_t)h * D);
        const int nc = ccnt[tid];
        float bb = FLT_MAX;
        int   bi = 0x7fffffff;
        if (nc <= CAP) {
            for (int i = 0; i < nc; ++i) {
                const int code = cand[tid][i];
                const float4* er = (const float4*)(keh + (size_t)code * D);
                float s = 0.f;
#pragma unroll 4
                for (int kq = 0; kq < 16; ++kq) {
                    float4 a4 = xr[kq]; float4 e4 = er[kq];
                    s = fmaf(a4.x, e4.x, s); s = fmaf(a4.y, e4.y, s);
                    s = fmaf(a4.z, e4.z, s); s = fmaf(a4.w, e4.w, s);
                }
                float sc = fmaf(-2.f, s, esqh[code]);
                if (sc < bb || (sc == bb && code < bi)) { bb = sc; bi = code; }
            }
        } else {
            // deterministic fallback: full exact scan, ascending => first-min
            for (int code = 0; code < C; ++code) {
                const float4* er = (const float4*)(keh + (size_t)code * D);
                float s = 0.f;
#pragma unroll 4
                for (int kq = 0; kq < 16; ++kq) {
                    float4 a4 = xr[kq]; float4 e4 = er[kq];
                    s = fmaf(a4.x, e4.x, s); s = fmaf(a4.y, e4.y, s);
                    s = fmaf(a4.z, e4.z, s); s = fmaf(a4.w, e4.w, s);
                }
                float sc = fmaf(-2.f, s, esqh[code]);
                if (sc < bb) { bb = sc; bi = code; }
            }
        }
        sidx[tid] = bi;
        outi[(size_t)(n0 + tid) * H + h] = (float)bi;          // [b,t,h]
        indw[((size_t)h << 14) + n0 + tid] = (unsigned short)bi;
        atomicAdd(&counts[(h << 11) + bi], 1u);                // fused histogram
    }
    __syncthreads();

    // ---- gather quantized vectors (no atomics) ----
#pragma unroll
    for (int ii = 0; ii < 2; ++ii) {
        const int v  = ii * 128 + (tid >> 1);
        const int db = (tid & 1) * 32;
        const int ci = sidx[v];
        const float* ev = keh + (size_t)ci * D + db;
        float* qo = outq + (size_t)(n0 + v) * HD + (size_t)h * D + db;
#pragma unroll
        for (int i = 0; i < 8; ++i)
            ((float4*)qo)[i] = ((const float4*)ev)[i];
    }
}

// ---------------------------------------------------------------------------
// Kernel 3: per-head exclusive prefix scan of counts -> off, cur
// ---------------------------------------------------------------------------
__global__ __launch_bounds__(256) void vq_scan_kernel(const unsigned int* __restrict__ counts,
                                                      unsigned int* __restrict__ off,
                                                      unsigned int* __restrict__ cur) {
    __shared__ unsigned int sa[C], sb[C];
    const int h   = blockIdx.x;
    const int tid = threadIdx.x;
#pragma unroll
    for (int j = 0; j < 8; ++j) sa[j * 256 + tid] = counts[(h << 11) + j * 256 + tid];
    __syncthreads();
    unsigned int* src = sa;
    unsigned int* dst = sb;
    for (int s = 1; s < C; s <<= 1) {
#pragma unroll
        for (int j = 0; j < 8; ++j) {
            const int c = j * 256 + tid;
            unsigned int v = src[c];
            if (c >= s) v += src[c - s];
            dst[c] = v;
        }
        __syncthreads();
        unsigned int* t = src; src = dst; dst = t;
    }
#pragma unroll
    for (int j = 0; j < 8; ++j) {
        const int c = j * 256 + tid;
        const unsigned int e = c ? src[c - 1] : 0u;
        off[(h << 11) + c] = e;
        cur[(h << 11) + c] = e;
    }
}

// ---------------------------------------------------------------------------
// Kernel 4: scatter vec-ids into per-code lists (u32 now, for clean scalar
//   loads in the reduce)
// ---------------------------------------------------------------------------
__global__ __launch_bounds__(256) void vq_scatter_kernel(const unsigned short* __restrict__ ind,
                                                         unsigned int* __restrict__ cur,
                                                         unsigned int* __restrict__ perm) {
    const int g = blockIdx.x * 256 + threadIdx.x;   // 131072
    const int h = g >> 14;
    const int n = g & 16383;
    const int c = ind[g];
    const unsigned int pos = atomicAdd(&cur[(h << 11) + c], 1u);
    perm[((size_t)h << 14) + pos] = (unsigned int)n;
}

// ---------------------------------------------------------------------------
// Kernel 5: segmented reduce + fused EMA lerp.
//   R16: one BLOCK (4 waves) per (head,code); waves stride entries mod 4,
//   each wave unrolled x4 (stride 16) with 4 independent f64 accumulators ->
//   16 loads in flight per segment. R15 had ONE wave + serial chain: the
//   most popular code (~2000 vectors, random-normal data is skewed) ran
//   2000 x ~220cyc dependent L2 loads = 186us tail (53% of total, occupancy
//   5%). Partials combined in FIXED order (a0..a3, then w0+w1+w2+w3) -> 
//   deterministic; f64 accum of <=16K f32 values has ~2^-39 rel error, so
//   the f32-rounded result is grouping-independent.
// ---------------------------------------------------------------------------
__global__ __launch_bounds__(256) void vq_reduce_kernel(const float* __restrict__ x,
                                                        const float* __restrict__ ke,
                                                        const unsigned int* __restrict__ perm,
                                                        const unsigned int* __restrict__ counts,
                                                        const unsigned int* __restrict__ off,
                                                        const int* __restrict__ ko,
                                                        float* __restrict__ outk) {
    __shared__ double sred[3][64];
    const int tid  = threadIdx.x;
    const int lane = tid & 63;
    const int w    = tid >> 6;
    const int pair = blockIdx.x;            // h*2048 + c
    const int h    = pair >> 11;

    const unsigned int cnt = counts[pair];
    const unsigned int o   = off[pair];
    const unsigned int* pl = perm + ((size_t)h << 14) + o;
    const float* xh = x + (size_t)h * D;    // + vid*HD + lane

    double a0 = 0.0, a1 = 0.0, a2 = 0.0, a3 = 0.0;
    unsigned int i = (unsigned int)w;
    for (; i + 12 < cnt; i += 16) {
        const unsigned int v0 = pl[i], v1 = pl[i + 4], v2 = pl[i + 8], v3 = pl[i + 12];
        a0 += (double)xh[(size_t)v0 * HD + lane];
        a1 += (double)xh[(size_t)v1 * HD + lane];
        a2 += (double)xh[(size_t)v2 * HD + lane];
        a3 += (double)xh[(size_t)v3 * HD + lane];
    }
    for (; i < cnt; i += 4)
        a0 += (double)xh[(size_t)pl[i] * HD + lane];
    const double part = ((a0 + a1) + a2) + a3;

    if (w) sred[w - 1][lane] = part;
    __syncthreads();
    if (w == 0) {
        const double acc = ((part + sred[0][lane]) + sred[1][lane]) + sred[2][lane];
        const float esum = (float)acc;
        const float kv   = ke[(size_t)pair * D + lane];
        const float ov   = ko[0] ? (kv + DECAYF * (esum - kv)) : kv;
        outk[(size_t)pair * D + lane] = ov;
    }
}

extern "C" void kernel_launch(void* const* d_in, const int* in_sizes, int n_in,
                              void* d_out, int out_size, void* d_ws, size_t ws_size,
                              hipStream_t stream) {
    const float* x  = (const float*)d_in[0];
    const float* ke = (const float*)d_in[1];
    const int*   ko = (const int*)d_in[2];

    float* out  = (float*)d_out;
    float* outq = out;                                   // 8,388,608 floats
    float* outi = out + (size_t)H * NPH * D;             // +131,072 floats
    float* outk = outi + (size_t)NPH * H;                // +1,048,576 floats

    // workspace layout
    float*          esq    = (float*)d_ws;                              // 16,384 f32
    unsigned short* keb2   = (unsigned short*)(esq + H * C);            // 1M u16 (swizzled)
    unsigned short* indw   = keb2 + (size_t)H * C * D;                  // 131,072 u16
    unsigned int*   counts = (unsigned int*)(indw + (size_t)H * NPH);   // 16,384 u32
    unsigned int*   offv   = counts + H * C;                            // 16,384 u32
    unsigned int*   curv   = offv + H * C;                              // 16,384 u32
    unsigned int*   perm   = curv + H * C;                              // 131,072 u32

    hipMemsetAsync(counts, 0, (size_t)H * C * sizeof(unsigned int), stream);

    vq_prep_kernel<<<(H * C) / 256, 256, 0, stream>>>(ke, keb2, esq);
    vq_main_kernel<<<512, 256, 0, stream>>>(x, keb2, ke, esq, outq, outi, indw, counts);
    vq_scan_kernel<<<H, 256, 0, stream>>>(counts, offv, curv);
    vq_scatter_kernel<<<512, 256, 0, stream>>>(indw, curv, perm);
    vq_reduce_kernel<<<H * C, 256, 0, stream>>>(x, ke, perm, counts, offv, ko, outk);
}

// Round 17
// 208.603 us; speedup vs baseline: 2.7537x; 1.0122x over previous
//
#include <hip/hip_runtime.h>
#include <float.h>

// VectorQuantize: h=8 heads, c=2048 codes, d=64, b=8, t=2048 (n=16384 vec/head)
#define H   8
#define C   2048
#define D   64
#define NPH 16384     // vectors per head (b*t)
#define HD  512       // h*d
#define DECAYF 0.9f
#define DELTA 3.0f    // candidate margin >= 2x worst-case bf16 score error (~0.6)
#define CAP 64        // per-vector candidate slots
#define VB  256       // vectors per block (512 blocks)

typedef __attribute__((ext_vector_type(8))) short short8v;   // 8 bf16 (4 VGPR)
typedef __attribute__((ext_vector_type(4))) float f32x4;

__device__ inline unsigned short f32_to_bf16_rne(float f) {
    unsigned int x = __float_as_uint(f);
    return (unsigned short)((x + 0x7FFFu + ((x >> 16) & 1u)) >> 16);
}

// ---------------------------------------------------------------------------
// Kernel 0: fused prep. Thread = one codebook row r = (h, ch*16+c):
//   esq[r]  = serial-fmaf sum of squares (bit-identical to passing rounds)
//   keb2    = bf16 codebook PRE-SWIZZLED into MFMA-fragment-linear order
//   (R15 win: main's B-load = two coalesced 1KB wave-loads per chunk).
// ---------------------------------------------------------------------------
__global__ __launch_bounds__(256) void vq_prep_kernel(const float* __restrict__ ke,
                                                      unsigned short* __restrict__ keb2,
                                                      float* __restrict__ esq) {
    const int row = blockIdx.x * 256 + threadIdx.x;   // 0 .. H*C-1
    const int c   = row & 15;
    const int ch  = (row >> 4) & 127;
    const int h   = row >> 11;
    const float* e = ke + (size_t)row * D;
    unsigned short* kb = keb2 + ((size_t)h * C * D) + (size_t)ch * 1024;
#pragma unroll
    for (int kf = 0; kf < 2; ++kf)
#pragma unroll
        for (int g = 0; g < 4; ++g) {
            float4 v0 = ((const float4*)e)[kf * 8 + g * 2];
            float4 v1 = ((const float4*)e)[kf * 8 + g * 2 + 1];
            short8v o;
            o[0] = (short)f32_to_bf16_rne(v0.x); o[1] = (short)f32_to_bf16_rne(v0.y);
            o[2] = (short)f32_to_bf16_rne(v0.z); o[3] = (short)f32_to_bf16_rne(v0.w);
            o[4] = (short)f32_to_bf16_rne(v1.x); o[5] = (short)f32_to_bf16_rne(v1.y);
            o[6] = (short)f32_to_bf16_rne(v1.z); o[7] = (short)f32_to_bf16_rne(v1.w);
            *(short8v*)(kb + kf * 512 + (g * 16 + c) * 8) = o;
        }
    float s = 0.f;
#pragma unroll
    for (int d = 0; d < D; ++d) s = fmaf(e[d], e[d], s);
    esq[row] = s;
}

// ---------------------------------------------------------------------------
// Kernel 1: MFMA screening + exact rescore.
//   R17 vs R16: B-prefetch depth 2 -> 4 named slots (both passes). R16's
//   main was 163us at 22us issue-floor: L2-latency-bound (depth-2 = ~208cyc
//   cover vs ~200-400cyc latency; grid 512 = only 2 blocks/CU to swap in).
//   Depth-4 = ~416cyc of compute between issue and use. Math/collection/
//   rescore bit-identical to passing R15/R16.
// ---------------------------------------------------------------------------
__global__ __launch_bounds__(256, 2)
void vq_main_kernel(const float* __restrict__ x,
                    const unsigned short* __restrict__ keb2,
                    const float* __restrict__ ke,
                    const float* __restrict__ esq,
                    float* __restrict__ outq,
                    float* __restrict__ outi,
                    unsigned short* __restrict__ indw,
                    unsigned int* __restrict__ counts) {
    __shared__ int            ccnt[VB];
    __shared__ unsigned short cand[VB][CAP];
    __shared__ int            sidx[VB];

    const int tid  = threadIdx.x;
    const int lane = tid & 63;
    const int w    = __builtin_amdgcn_readfirstlane(tid >> 6);
    const int h    = blockIdx.x & 7;
    const int n0   = (blockIdx.x >> 3) * VB;

    const unsigned short* keb2h = keb2 + (size_t)h * C * D;
    const float* keh  = ke  + (size_t)h * C * D;
    const float* esqh = esq + (size_t)h * C;

    ccnt[tid] = 0;
    __syncthreads();

    const int col = lane & 15;        // code col within 16-tile
    const int kg  = (lane >> 4) * 8;  // this lane's k-group base

    // ---- A-frags: lane's 4 vec-rows x 64 k, bf16, persistent ----
    short8v afr[4][2];
#pragma unroll
    for (int vt = 0; vt < 4; ++vt) {
        const float* xp = x + (size_t)(n0 + w * 64 + vt * 16 + col) * HD
                            + (size_t)h * D + kg;
#pragma unroll
        for (int kf = 0; kf < 2; ++kf) {
            float4 u0 = *(const float4*)(xp + kf * 32);
            float4 u1 = *(const float4*)(xp + kf * 32 + 4);
            short8v a;
            a[0] = (short)f32_to_bf16_rne(u0.x); a[1] = (short)f32_to_bf16_rne(u0.y);
            a[2] = (short)f32_to_bf16_rne(u0.z); a[3] = (short)f32_to_bf16_rne(u0.w);
            a[4] = (short)f32_to_bf16_rne(u1.x); a[5] = (short)f32_to_bf16_rne(u1.y);
            a[6] = (short)f32_to_bf16_rne(u1.z); a[7] = (short)f32_to_bf16_rne(u1.w);
            afr[vt][kf] = a;
        }
    }

    float amin[16];
#pragma unroll
    for (int s = 0; s < 16; ++s) amin[s] = FLT_MAX;

    // coalesced fragment load: B0 = kb[lane], B1 = kb[64+lane]
#define LOADB2(CH, B0, B1, EQ)                                                 \
    {                                                                          \
        const short8v* kb = (const short8v*)(keb2h + (size_t)(CH) * 1024);     \
        B0 = kb[lane];                                                         \
        B1 = kb[64 + lane];                                                    \
        EQ = esqh[((CH) << 4) + col];                                          \
    }

    // MFMA + running-min epilogue (pass 1)
#define STEP1(C0V, C1V, QV)                                                    \
    {                                                                          \
        _Pragma("unroll")                                                      \
        for (int vt = 0; vt < 4; ++vt) {                                       \
            f32x4 acc = {0.f, 0.f, 0.f, 0.f};                                  \
            acc = __builtin_amdgcn_mfma_f32_16x16x32_bf16(afr[vt][0], C0V, acc, 0, 0, 0); \
            acc = __builtin_amdgcn_mfma_f32_16x16x32_bf16(afr[vt][1], C1V, acc, 0, 0, 0); \
            _Pragma("unroll")                                                  \
            for (int r = 0; r < 4; ++r) {                                      \
                float sc = fmaf(-2.f, acc[r], QV);                             \
                amin[vt * 4 + r] = fminf(amin[vt * 4 + r], sc);                \
            }                                                                  \
        }                                                                      \
    }

    // MFMA + candidate-collect epilogue (pass 2)
#define STEP2(C0V, C1V, QV, CB)                                                \
    {                                                                          \
        _Pragma("unroll")                                                      \
        for (int vt = 0; vt < 4; ++vt) {                                       \
            f32x4 acc = {0.f, 0.f, 0.f, 0.f};                                  \
            acc = __builtin_amdgcn_mfma_f32_16x16x32_bf16(afr[vt][0], C0V, acc, 0, 0, 0); \
            acc = __builtin_amdgcn_mfma_f32_16x16x32_bf16(afr[vt][1], C1V, acc, 0, 0, 0); \
            _Pragma("unroll")                                                  \
            for (int r = 0; r < 4; ++r) {                                      \
                float sc = fmaf(-2.f, acc[r], QV);                             \
                if (sc <= amin[vt * 4 + r] + DELTA) {                          \
                    const int vec = w * 64 + vt * 16 + ((lane >> 4) << 2) + r; \
                    int pos = atomicAdd(&ccnt[vec], 1);                        \
                    if (pos < CAP) cand[vec][pos] = (unsigned short)((CB) + col); \
                }                                                              \
            }                                                                  \
        }                                                                      \
    }

    // ================= pass 1: per-vector approx min (depth-4 pipeline) ====
    {
        short8v s0a, s0b, s1a, s1b, s2a, s2b, s3a, s3b;
        float   q0, q1, q2, q3;
        LOADB2(0, s0a, s0b, q0);
        LOADB2(1, s1a, s1b, q1);
        LOADB2(2, s2a, s2b, q2);
        LOADB2(3, s3a, s3b, q3);
#pragma unroll 1
        for (int g = 0; g < 32; ++g) {
            {
                short8v c0 = s0a, c1 = s0b; float q = q0;
                LOADB2((4 * g + 4) & 127, s0a, s0b, q0);
                STEP1(c0, c1, q);
            }
            {
                short8v c0 = s1a, c1 = s1b; float q = q1;
                LOADB2((4 * g + 5) & 127, s1a, s1b, q1);
                STEP1(c0, c1, q);
            }
            {
                short8v c0 = s2a, c1 = s2b; float q = q2;
                LOADB2((4 * g + 6) & 127, s2a, s2b, q2);
                STEP1(c0, c1, q);
            }
            {
                short8v c0 = s3a, c1 = s3b; float q = q3;
                LOADB2((4 * g + 7) & 127, s3a, s3b, q3);
                STEP1(c0, c1, q);
            }
        }
    }

    // cross-lane min over the 16 lanes sharing (lane>>4)
#pragma unroll
    for (int s = 0; s < 16; ++s) {
        float v = amin[s];
        v = fminf(v, __shfl_xor(v, 1));
        v = fminf(v, __shfl_xor(v, 2));
        v = fminf(v, __shfl_xor(v, 4));
        v = fminf(v, __shfl_xor(v, 8));
        amin[s] = v;
    }

    // ================= pass 2: collect candidates per VECTOR ================
    {
        short8v s0a, s0b, s1a, s1b, s2a, s2b, s3a, s3b;
        float   q0, q1, q2, q3;
        LOADB2(0, s0a, s0b, q0);
        LOADB2(1, s1a, s1b, q1);
        LOADB2(2, s2a, s2b, q2);
        LOADB2(3, s3a, s3b, q3);
#pragma unroll 1
        for (int g = 0; g < 32; ++g) {
            {
                short8v c0 = s0a, c1 = s0b; float q = q0;
                LOADB2((4 * g + 4) & 127, s0a, s0b, q0);
                STEP2(c0, c1, q, (4 * g + 0) << 4);
            }
            {
                short8v c0 = s1a, c1 = s1b; float q = q1;
                LOADB2((4 * g + 5) & 127, s1a, s1b, q1);
                STEP2(c0, c1, q, (4 * g + 1) << 4);
            }
            {
                short8v c0 = s2a, c1 = s2b; float q = q2;
                LOADB2((4 * g + 6) & 127, s2a, s2b, q2);
                STEP2(c0, c1, q, (4 * g + 2) << 4);
            }
            {
                short8v c0 = s3a, c1 = s3b; float q = q3;
                LOADB2((4 * g + 7) & 127, s3a, s3b, q3);
                STEP2(c0, c1, q, (4 * g + 3) << 4);
            }
        }
    }
    __syncthreads();

    // ================= exact f32 rescore: thread tid <-> vec tid ============
    {
        const float4* xr = (const float4*)(x + (size_t)(n0 + tid) * HD + (size_t)h * D);
        const int nc = ccnt[tid];
        float bb = FLT_MAX;
        int   bi = 0x7fffffff;
        if (nc <= CAP) {
            for (int i = 0; i < nc; ++i) {
                const int code = cand[tid][i];
                const float4* er = (const float4*)(keh + (size_t)code * D);
                float s = 0.f;
#pragma unroll 4
                for (int kq = 0; kq < 16; ++kq) {
                    float4 a4 = xr[kq]; float4 e4 = er[kq];
                    s = fmaf(a4.x, e4.x, s); s = fmaf(a4.y, e4.y, s);
                    s = fmaf(a4.z, e4.z, s); s = fmaf(a4.w, e4.w, s);
                }
                float sc = fmaf(-2.f, s, esqh[code]);
                if (sc < bb || (sc == bb && code < bi)) { bb = sc; bi = code; }
            }
        } else {
            // deterministic fallback: full exact scan, ascending => first-min
            for (int code = 0; code < C; ++code) {
                const float4* er = (const float4*)(keh + (size_t)code * D);
                float s = 0.f;
#pragma unroll 4
                for (int kq = 0; kq < 16; ++kq) {
                    float4 a4 = xr[kq]; float4 e4 = er[kq];
                    s = fmaf(a4.x, e4.x, s); s = fmaf(a4.y, e4.y, s);
                    s = fmaf(a4.z, e4.z, s); s = fmaf(a4.w, e4.w, s);
                }
                float sc = fmaf(-2.f, s, esqh[code]);
                if (sc < bb) { bb = sc; bi = code; }
            }
        }
        sidx[tid] = bi;
        outi[(size_t)(n0 + tid) * H + h] = (float)bi;          // [b,t,h]
        indw[((size_t)h << 14) + n0 + tid] = (unsigned short)bi;
        atomicAdd(&counts[(h << 11) + bi], 1u);                // fused histogram
    }
    __syncthreads();

    // ---- gather quantized vectors (no atomics) ----
#pragma unroll
    for (int ii = 0; ii < 2; ++ii) {
        const int v  = ii * 128 + (tid >> 1);
        const int db = (tid & 1) * 32;
        const int ci = sidx[v];
        const float* ev = keh + (size_t)ci * D + db;
        float* qo = outq + (size_t)(n0 + v) * HD + (size_t)h * D + db;
#pragma unroll
        for (int i = 0; i < 8; ++i)
            ((float4*)qo)[i] = ((const float4*)ev)[i];
    }
}

// ---------------------------------------------------------------------------
// Kernel 3: per-head exclusive prefix scan of counts -> off, cur
// ---------------------------------------------------------------------------
__global__ __launch_bounds__(256) void vq_scan_kernel(const unsigned int* __restrict__ counts,
                                                      unsigned int* __restrict__ off,
                                                      unsigned int* __restrict__ cur) {
    __shared__ unsigned int sa[C], sb[C];
    const int h   = blockIdx.x;
    const int tid = threadIdx.x;
#pragma unroll
    for (int j = 0; j < 8; ++j) sa[j * 256 + tid] = counts[(h << 11) + j * 256 + tid];
    __syncthreads();
    unsigned int* src = sa;
    unsigned int* dst = sb;
    for (int s = 1; s < C; s <<= 1) {
#pragma unroll
        for (int j = 0; j < 8; ++j) {
            const int c = j * 256 + tid;
            unsigned int v = src[c];
            if (c >= s) v += src[c - s];
            dst[c] = v;
        }
        __syncthreads();
        unsigned int* t = src; src = dst; dst = t;
    }
#pragma unroll
    for (int j = 0; j < 8; ++j) {
        const int c = j * 256 + tid;
        const unsigned int e = c ? src[c - 1] : 0u;
        off[(h << 11) + c] = e;
        cur[(h << 11) + c] = e;
    }
}

// ---------------------------------------------------------------------------
// Kernel 4: scatter vec-ids into per-code lists (131K cursor atomics)
// ---------------------------------------------------------------------------
__global__ __launch_bounds__(256) void vq_scatter_kernel(const unsigned short* __restrict__ ind,
                                                         unsigned int* __restrict__ cur,
                                                         unsigned int* __restrict__ perm) {
    const int g = blockIdx.x * 256 + threadIdx.x;   // 131072
    const int h = g >> 14;
    const int n = g & 16383;
    const int c = ind[g];
    const unsigned int pos = atomicAdd(&cur[(h << 11) + c], 1u);
    perm[((size_t)h << 14) + pos] = (unsigned int)n;
}

// ---------------------------------------------------------------------------
// Kernel 5: segmented reduce + fused EMA lerp (R16 structure -- 186->~10us).
//   One block per (head,code); 4 waves stride entries; 4 f64 accs per wave;
//   fixed combine order => deterministic.
// ---------------------------------------------------------------------------
__global__ __launch_bounds__(256) void vq_reduce_kernel(const float* __restrict__ x,
                                                        const float* __restrict__ ke,
                                                        const unsigned int* __restrict__ perm,
                                                        const unsigned int* __restrict__ counts,
                                                        const unsigned int* __restrict__ off,
                                                        const int* __restrict__ ko,
                                                        float* __restrict__ outk) {
    __shared__ double sred[3][64];
    const int tid  = threadIdx.x;
    const int lane = tid & 63;
    const int w    = tid >> 6;
    const int pair = blockIdx.x;            // h*2048 + c
    const int h    = pair >> 11;

    const unsigned int cnt = counts[pair];
    const unsigned int o   = off[pair];
    const unsigned int* pl = perm + ((size_t)h << 14) + o;
    const float* xh = x + (size_t)h * D;    // + vid*HD + lane

    double a0 = 0.0, a1 = 0.0, a2 = 0.0, a3 = 0.0;
    unsigned int i = (unsigned int)w;
    for (; i + 12 < cnt; i += 16) {
        const unsigned int v0 = pl[i], v1 = pl[i + 4], v2 = pl[i + 8], v3 = pl[i + 12];
        a0 += (double)xh[(size_t)v0 * HD + lane];
        a1 += (double)xh[(size_t)v1 * HD + lane];
        a2 += (double)xh[(size_t)v2 * HD + lane];
        a3 += (double)xh[(size_t)v3 * HD + lane];
    }
    for (; i < cnt; i += 4)
        a0 += (double)xh[(size_t)pl[i] * HD + lane];
    const double part = ((a0 + a1) + a2) + a3;

    if (w) sred[w - 1][lane] = part;
    __syncthreads();
    if (w == 0) {
        const double acc = ((part + sred[0][lane]) + sred[1][lane]) + sred[2][lane];
        const float esum = (float)acc;
        const float kv   = ke[(size_t)pair * D + lane];
        const float ov   = ko[0] ? (kv + DECAYF * (esum - kv)) : kv;
        outk[(size_t)pair * D + lane] = ov;
    }
}

extern "C" void kernel_launch(void* const* d_in, const int* in_sizes, int n_in,
                              void* d_out, int out_size, void* d_ws, size_t ws_size,
                              hipStream_t stream) {
    const float* x  = (const float*)d_in[0];
    const float* ke = (const float*)d_in[1];
    const int*   ko = (const int*)d_in[2];

    float* out  = (float*)d_out;
    float* outq = out;                                   // 8,388,608 floats
    float* outi = out + (size_t)H * NPH * D;             // +131,072 floats
    float* outk = outi + (size_t)NPH * H;                // +1,048,576 floats

    // workspace layout
    float*          esq    = (float*)d_ws;                              // 16,384 f32
    unsigned short* keb2   = (unsigned short*)(esq + H * C);            // 1M u16 (swizzled)
    unsigned short* indw   = keb2 + (size_t)H * C * D;                  // 131,072 u16
    unsigned int*   counts = (unsigned int*)(indw + (size_t)H * NPH);   // 16,384 u32
    unsigned int*   offv   = counts + H * C;                            // 16,384 u32
    unsigned int*   curv   = offv + H * C;                              // 16,384 u32
    unsigned int*   perm   = curv + H * C;                              // 131,072 u32

    hipMemsetAsync(counts, 0, (size_t)H * C * sizeof(unsigned int), stream);

    vq_prep_kernel<<<(H * C) / 256, 256, 0, stream>>>(ke, keb2, esq);
    vq_main_kernel<<<512, 256, 0, stream>>>(x, keb2, ke, esq, outq, outi, indw, counts);
    vq_scan_kernel<<<H, 256, 0, stream>>>(counts, offv, curv);
    vq_scatter_kernel<<<512, 256, 0, stream>>>(indw, curv, perm);
    vq_reduce_kernel<<<H * C, 256, 0, stream>>>(x, ke, perm, counts, offv, ko, outk);
}